// Round 12
// baseline (283.312 us; speedup 1.0000x reference)
//
#include <hip/hip_runtime.h>
#include <hip/hip_bf16.h>

typedef __hip_bfloat16 HB;
typedef __attribute__((ext_vector_type(8))) short short8;
typedef __attribute__((ext_vector_type(4))) short short4v;
typedef __attribute__((ext_vector_type(4))) float f32x4;
typedef __attribute__((ext_vector_type(2))) unsigned int uint2v;
typedef __attribute__((ext_vector_type(4))) unsigned int uint4v;

constexpr int Bn = 4, Nn = 2048, Dm = 128, Hh = 4;
constexpr int MN = Bn * Nn;              // 8192 rows
constexpr size_t SZ = (size_t)MN * Dm;   // 1,048,576 elems per [B,N,128] buffer

static __device__ __forceinline__ short f2bs(float x) {   // RNE
    __hip_bfloat16 h = __float2bfloat16(x);
    return __builtin_bit_cast(short, h);
}
static __device__ __forceinline__ unsigned short f2bh(float x) {  // round-half-up
    return (unsigned short)((__builtin_bit_cast(unsigned int, x) + 0x8000u) >> 16);
}
static __device__ __forceinline__ unsigned int pk2(float lo, float hi) {
    unsigned int a = __builtin_bit_cast(unsigned int, lo) + 0x8000u;
    unsigned int b = __builtin_bit_cast(unsigned int, hi) + 0x8000u;
#if __has_builtin(__builtin_amdgcn_perm)
    return __builtin_amdgcn_perm(b, a, 0x07060302u);
#else
    return (a >> 16) | (b & 0xFFFF0000u);
#endif
}
// fast 2^x (v_exp_f32)
static __device__ __forceinline__ float ex2(float x) {
#if __has_builtin(__builtin_amdgcn_exp2f)
    return __builtin_amdgcn_exp2f(x);
#else
    return exp2f(x);
#endif
}
// sigmoid(s/sqrt(128)) folded: rcp(1 + 2^(s*c)), c = -log2e/sqrt(128)
#define NSC2 (-0.12751884772864078f)

// K bf16 head-packed layout: Kh[bh][n][32dh]
static __device__ __forceinline__ size_t kh_idx(int row, int col) {
    return ((size_t)((row >> 11) * 4 + (col >> 5)) * 2048 + (row & 2047)) * 32 + (col & 31);
}

// ================= weight pre-swizzle (UNCHANGED, passing) =================
__global__ void k_wprep(const float* __restrict__ Wa, const float* __restrict__ Wb,
                        const float* __restrict__ Wc, const float* __restrict__ Wd,
                        const float* __restrict__ We, const float* __restrict__ Wf,
                        const float* __restrict__ Wg, const float* __restrict__ Wh,
                        const float* __restrict__ Wi, const float* __restrict__ Wj,
                        HB* __restrict__ WtAll) {
    const float* src;
    switch (blockIdx.x) {
        case 0: src = Wa; break; case 1: src = Wb; break;
        case 2: src = Wc; break; case 3: src = Wd; break;
        case 4: src = We; break; case 5: src = Wf; break;
        case 6: src = Wg; break; case 7: src = Wh; break;
        case 8: src = Wi; break; default: src = Wj; break;
    }
    HB* dst = WtAll + (size_t)blockIdx.x * 16384;
    #pragma unroll
    for (int it = 0; it < 2; ++it) {
        int idx = blockIdx.y * 512 + it * 256 + threadIdx.x;   // 0..2047
        int g = idx >> 7, c = idx & 127;
        short8 p;
        #pragma unroll
        for (int j = 0; j < 8; ++j) p[j] = f2bs(src[(size_t)(g * 8 + j) * 128 + c]);
        *(short8*)((short*)dst + (size_t)idx * 8) = p;
    }
}

// ================= MFMA linear (UNCHANGED, passing) =================
template<int NW, int RELU, int NEXTRA, int FUSE>
__global__ __launch_bounds__(512) void k_linm(
        const float* __restrict__ A, const float* __restrict__ extra,
        const HB* __restrict__ Wt0, const float* __restrict__ b0,
        const HB* __restrict__ Wt1, const float* __restrict__ b1,
        const HB* __restrict__ Wt2, const float* __restrict__ b2,
        float* __restrict__ C0, float* __restrict__ C1,
        HB* __restrict__ Qb, HB* __restrict__ Kb, HB* __restrict__ Vt) {
    const int tid = threadIdx.x;
    const int w = tid >> 6, lane = tid & 63, l15 = lane & 15, quad = lane >> 4;
    const int row0 = blockIdx.x * 32 + (w >> 2) * 16;
    const int cbase = (w & 3) * 32;

    short8 af[4];
    #pragma unroll
    for (int kc = 0; kc < 4; ++kc) {
        const float* ap = A + (size_t)(row0 + l15) * 128 + kc * 32 + quad * 8;
        float4 x0 = *(const float4*)ap;
        float4 x1 = *(const float4*)(ap + 4);
        if (NEXTRA) {
            const float* ep = extra + (size_t)(row0 + l15) * 128 + kc * 32 + quad * 8;
            float4 e0 = *(const float4*)ep, e1 = *(const float4*)(ep + 4);
            x0.x += e0.x; x0.y += e0.y; x0.z += e0.z; x0.w += e0.w;
            x1.x += e1.x; x1.y += e1.y; x1.z += e1.z; x1.w += e1.w;
        }
        uint4v u;
        u[0] = pk2(x0.x, x0.y); u[1] = pk2(x0.z, x0.w);
        u[2] = pk2(x1.x, x1.y); u[3] = pk2(x1.z, x1.w);
        af[kc] = __builtin_bit_cast(short8, u);
    }

    f32x4 zero = {0.f, 0.f, 0.f, 0.f};
    #pragma unroll
    for (int ct = 0; ct < 2; ++ct) {
        const int col = cbase + ct * 16 + l15;
        #pragma unroll
        for (int s = 0; s < NW; ++s) {
            const HB* Wt = (s == 0) ? Wt0 : (s == 1) ? Wt1 : Wt2;
            const float* bs = (s == 0) ? b0 : (s == 1) ? b1 : b2;
            f32x4 acc = zero;
            #pragma unroll
            for (int kc = 0; kc < 4; ++kc) {
                short8 bf = *(const short8*)((const short*)Wt + ((size_t)(kc * 4 + quad) * 128 + col) * 8);
                acc = __builtin_amdgcn_mfma_f32_16x16x32_bf16(af[kc], bf, acc, 0, 0, 0);
            }
            float bb = bs[col];
            if (s == 0 || !FUSE) {
                float* Cs = (s == 0) ? C0 : C1;
                #pragma unroll
                for (int r = 0; r < 4; ++r) {
                    int row = row0 + quad * 4 + r;
                    float v = acc[r] + bb;
                    if (RELU && s == 0) {
                        float st = A[(size_t)row * 128 + col];
                        if (NEXTRA) st += extra[(size_t)row * 128 + col];
                        v = fmaxf(v, 0.f) + st;
                    }
                    Cs[(size_t)row * 128 + col] = v;
                    if (FUSE && s == 0)
                        ((unsigned short*)Qb)[(size_t)row * 128 + col] = f2bh(v);
                }
            } else if (s == 1) {            // K -> head-packed bf16 Kh[bh][n][32]
                #pragma unroll
                for (int r = 0; r < 4; ++r) {
                    int row = row0 + quad * 4 + r;
                    ((unsigned short*)Kb)[kh_idx(row, col)] = f2bh(acc[r] + bb);
                }
            } else {
                int b_ = row0 >> 11;
                int mloc = (row0 + quad * 4) & 2047;
                int slotb = (mloc & ~31) + (((mloc & 15) >> 2) << 3) + (((mloc >> 4) & 1) << 2);
                int h_ = col >> 5, dh = col & 31;
                uint2v pv;
                pv[0] = pk2(acc[0] + bb, acc[1] + bb);
                pv[1] = pk2(acc[2] + bb, acc[3] + bb);
                *(short4v*)((short*)Vt + ((size_t)((b_ * 4 + h_) * 32 + dh)) * 2048 + slotb)
                    = __builtin_bit_cast(short4v, pv);
            }
        }
    }
}

// ================= fused O-projection + downstream GEMMs (UNCHANGED, passing) =================
template<int NQKV, int FUSE>
__global__ __launch_bounds__(512) void k_fused(
        const float* __restrict__ A, const float* __restrict__ extra,
        const HB* __restrict__ WtO, const float* __restrict__ bO,
        const HB* __restrict__ Wt0, const float* __restrict__ b0,
        const HB* __restrict__ Wt1, const float* __restrict__ b1,
        const HB* __restrict__ Wt2, const float* __restrict__ b2,
        float* __restrict__ C0, float* __restrict__ C1,
        HB* __restrict__ Qb, HB* __restrict__ Kb, HB* __restrict__ Vt) {
    const int tid = threadIdx.x;
    const int w = tid >> 6, lane = tid & 63, l15 = lane & 15, quad = lane >> 4;
    const int lrow0 = (w >> 2) * 16;
    const int row0 = blockIdx.x * 32 + lrow0;
    const int cbase = (w & 3) * 32;

    __shared__ float xs[32 * 132];

    short8 af[4];
    #pragma unroll
    for (int kc = 0; kc < 4; ++kc) {
        const float* ap = A + (size_t)(row0 + l15) * 128 + kc * 32 + quad * 8;
        float4 x0 = *(const float4*)ap;
        float4 x1 = *(const float4*)(ap + 4);
        const float* ep = extra + (size_t)(row0 + l15) * 128 + kc * 32 + quad * 8;
        float4 e0 = *(const float4*)ep, e1 = *(const float4*)(ep + 4);
        x0.x += e0.x; x0.y += e0.y; x0.z += e0.z; x0.w += e0.w;
        x1.x += e1.x; x1.y += e1.y; x1.z += e1.z; x1.w += e1.w;
        uint4v u;
        u[0] = pk2(x0.x, x0.y); u[1] = pk2(x0.z, x0.w);
        u[2] = pk2(x1.x, x1.y); u[3] = pk2(x1.z, x1.w);
        af[kc] = __builtin_bit_cast(short8, u);
    }

    f32x4 zero = {0.f, 0.f, 0.f, 0.f};

    #pragma unroll
    for (int ct = 0; ct < 2; ++ct) {
        const int col = cbase + ct * 16 + l15;
        f32x4 acc = zero;
        #pragma unroll
        for (int kc = 0; kc < 4; ++kc) {
            short8 bf = *(const short8*)((const short*)WtO + ((size_t)(kc * 4 + quad) * 128 + col) * 8);
            acc = __builtin_amdgcn_mfma_f32_16x16x32_bf16(af[kc], bf, acc, 0, 0, 0);
        }
        float bb = bO[col];
        #pragma unroll
        for (int r = 0; r < 4; ++r) {
            int row = row0 + quad * 4 + r;
            float st = A[(size_t)row * 128 + col] + extra[(size_t)row * 128 + col];
            xs[(lrow0 + quad * 4 + r) * 132 + col] = fmaxf(acc[r] + bb, 0.f) + st;
        }
    }
    __syncthreads();

    short8 a2[4];
    {
        const float* xrow = xs + (size_t)(lrow0 + l15) * 132;
        #pragma unroll
        for (int kc = 0; kc < 4; ++kc) {
            f32x4 x0 = *(const f32x4*)(xrow + kc * 32 + quad * 8);
            f32x4 x1 = *(const f32x4*)(xrow + kc * 32 + quad * 8 + 4);
            uint4v u;
            u[0] = pk2(x0[0], x0[1]); u[1] = pk2(x0[2], x0[3]);
            u[2] = pk2(x1[0], x1[1]); u[3] = pk2(x1[2], x1[3]);
            a2[kc] = __builtin_bit_cast(short8, u);
        }
    }

    #pragma unroll
    for (int ct = 0; ct < 2; ++ct) {
        const int col = cbase + ct * 16 + l15;
        #pragma unroll
        for (int s = 0; s < NQKV; ++s) {
            const HB* Wt = (s == 0) ? Wt0 : (s == 1) ? Wt1 : Wt2;
            const float* bs = (s == 0) ? b0 : (s == 1) ? b1 : b2;
            f32x4 acc = zero;
            #pragma unroll
            for (int kc = 0; kc < 4; ++kc) {
                short8 bf = *(const short8*)((const short*)Wt + ((size_t)(kc * 4 + quad) * 128 + col) * 8);
                acc = __builtin_amdgcn_mfma_f32_16x16x32_bf16(a2[kc], bf, acc, 0, 0, 0);
            }
            float bb = bs[col];
            if (s == 0 || !FUSE) {
                float* Cs = (s == 0) ? C0 : C1;
                #pragma unroll
                for (int r = 0; r < 4; ++r) {
                    int row = row0 + quad * 4 + r;
                    float v = acc[r] + bb;
                    Cs[(size_t)row * 128 + col] = v;
                    if (FUSE && s == 0)
                        ((unsigned short*)Qb)[(size_t)row * 128 + col] = f2bh(v);
                }
            } else if (s == 1) {            // K -> head-packed bf16 Kh[bh][n][32]
                #pragma unroll
                for (int r = 0; r < 4; ++r) {
                    int row = row0 + quad * 4 + r;
                    ((unsigned short*)Kb)[kh_idx(row, col)] = f2bh(acc[r] + bb);
                }
            } else {
                int b_ = row0 >> 11;
                int mloc = (row0 + quad * 4) & 2047;
                int slotb = (mloc & ~31) + (((mloc & 15) >> 2) << 3) + (((mloc >> 4) & 1) << 2);
                int h_ = col >> 5, dh = col & 31;
                uint2v pv;
                pv[0] = pk2(acc[0] + bb, acc[1] + bb);
                pv[1] = pk2(acc[2] + bb, acc[3] + bb);
                *(short4v*)((short*)Vt + ((size_t)((b_ * 4 + h_) * 32 + dh)) * 2048 + slotb)
                    = __builtin_bit_cast(short4v, pv);
            }
        }
    }
}

// ================= MFMA sigmoid attention v5 (UNCHANGED from R11, passing) =================
__global__ __launch_bounds__(512, 4) void k_attn4(const HB* __restrict__ Qb, const HB* __restrict__ Kbf,
                                                  const HB* __restrict__ Vt, float* __restrict__ Opart) {
    const int tid = threadIdx.x;
    const int w = tid >> 6, lane = tid & 63, l15 = lane & 15, quad = lane >> 4;
    const int bh = blockIdx.x & 15, qg2 = blockIdx.x >> 4;
    const int b = bh >> 2, h = bh & 3;
    const int q0row = qg2 * 64;

    __shared__ float ldsacc[8][64][36];

    short8 aq[4];
    {
        const short* qp = (const short*)Qb + (size_t)(b * Nn + q0row) * 128 + h * 32 + quad * 8;
        #pragma unroll
        for (int qa = 0; qa < 4; ++qa)
            aq[qa] = *(const short8*)(qp + (size_t)(qa * 16 + l15) * 128);
    }

    f32x4 zero = {0.f, 0.f, 0.f, 0.f};
    f32x4 o[4][2];
    #pragma unroll
    for (int qa = 0; qa < 4; ++qa) { o[qa][0] = zero; o[qa][1] = zero; }

    const short* Kb = (const short*)Kbf + (size_t)bh * Nn * 32;   // head-packed
    const short* Vb = (const short*)Vt + (size_t)bh * 32 * Nn;

    for (int m0 = w * 256; m0 < w * 256 + 256; m0 += 64) {
        short8 kb[4];
        #pragma unroll
        for (int mc = 0; mc < 4; ++mc)
            kb[mc] = *(const short8*)(Kb + (size_t)(m0 + mc * 16 + l15) * 32 + quad * 8);
        short8 vf[2][2];
        #pragma unroll
        for (int t = 0; t < 2; ++t)
            #pragma unroll
            for (int u = 0; u < 2; ++u)
                vf[t][u] = *(const short8*)(Vb + (size_t)(t * 16 + l15) * Nn + m0 + u * 32 + quad * 8);

        #pragma unroll
        for (int qa = 0; qa < 4; ++qa) {
            f32x4 s[4];
            #pragma unroll
            for (int mc = 0; mc < 4; ++mc)
                s[mc] = __builtin_amdgcn_mfma_f32_16x16x32_bf16(kb[mc], aq[qa], zero, 0, 0, 0);
            #pragma unroll
            for (int u = 0; u < 2; ++u) {
                f32x4 lo = s[2 * u], hi = s[2 * u + 1];
                float p0 = __builtin_amdgcn_rcpf(1.f + ex2(lo[0] * NSC2));
                float p1 = __builtin_amdgcn_rcpf(1.f + ex2(lo[1] * NSC2));
                float p2 = __builtin_amdgcn_rcpf(1.f + ex2(lo[2] * NSC2));
                float p3 = __builtin_amdgcn_rcpf(1.f + ex2(lo[3] * NSC2));
                float p4 = __builtin_amdgcn_rcpf(1.f + ex2(hi[0] * NSC2));
                float p5 = __builtin_amdgcn_rcpf(1.f + ex2(hi[1] * NSC2));
                float p6 = __builtin_amdgcn_rcpf(1.f + ex2(hi[2] * NSC2));
                float p7 = __builtin_amdgcn_rcpf(1.f + ex2(hi[3] * NSC2));
                uint4v pu;
                pu[0] = pk2(p0, p1); pu[1] = pk2(p2, p3);
                pu[2] = pk2(p4, p5); pu[3] = pk2(p6, p7);
                short8 pf = __builtin_bit_cast(short8, pu);
                #pragma unroll
                for (int t = 0; t < 2; ++t)
                    o[qa][t] = __builtin_amdgcn_mfma_f32_16x16x32_bf16(vf[t][u], pf, o[qa][t], 0, 0, 0);
            }
        }
    }

    #pragma unroll
    for (int qa = 0; qa < 4; ++qa)
        #pragma unroll
        for (int t = 0; t < 2; ++t)
            *(f32x4*)&ldsacc[w][qa * 16 + l15][t * 16 + quad * 4] = o[qa][t];
    __syncthreads();
    const int row = tid >> 3, cc = (tid & 7) * 4;
    f32x4 sum = zero;
    #pragma unroll
    for (int ww = 0; ww < 8; ++ww) {
        f32x4 r = *(f32x4*)&ldsacc[ww][row][cc];
        sum += r;
    }
    *(f32x4*)(Opart + (size_t)(b * Nn + q0row + row) * 128 + h * 32 + cc) = sum;
}

// ================= PMA attention (UNCHANGED, passing) =================
__global__ void k_pma2(const float* __restrict__ S, const float* __restrict__ Wq, const float* __restrict__ bq,
                       const float* __restrict__ Kp, const float* __restrict__ Vp,
                       float* __restrict__ P0part) {
    const int bh = blockIdx.x, b = bh >> 2, h = bh & 3;
    const int ms = blockIdx.y;
    const int tid = threadIdx.x;
    __shared__ float4 qs4[8];
    float* qs = (float*)qs4;
    if (tid < 32) {
        float a = bq[h * 32 + tid];
        for (int k = 0; k < 128; ++k)
            a = fmaf(S[k], Wq[k * Dm + h * 32 + tid], a);
        qs[tid] = a;
    }
    __syncthreads();

    float4 q[8];
    #pragma unroll
    for (int i = 0; i < 8; ++i) q[i] = qs4[i];

    const size_t base = (size_t)b * Nn * Dm + h * 32;
    const int m = ms * 256 + tid;

    const float4* kp = (const float4*)(Kp + base + (size_t)m * Dm);
    const float4* vp = (const float4*)(Vp + base + (size_t)m * Dm);
    float d0 = 0.f, d1 = 0.f, d2 = 0.f, d3 = 0.f;
    #pragma unroll
    for (int c = 0; c < 8; c += 4) {
        float4 k0 = kp[c+0], k1 = kp[c+1], k2 = kp[c+2], k3 = kp[c+3];
        d0 += q[c+0].x*k0.x + q[c+0].y*k0.y + q[c+0].z*k0.z + q[c+0].w*k0.w;
        d1 += q[c+1].x*k1.x + q[c+1].y*k1.y + q[c+1].z*k1.z + q[c+1].w*k1.w;
        d2 += q[c+2].x*k2.x + q[c+2].y*k2.y + q[c+2].z*k2.z + q[c+2].w*k2.w;
        d3 += q[c+3].x*k3.x + q[c+3].y*k3.y + q[c+3].z*k3.z + q[c+3].w*k3.w;
    }
    float dot = (d0 + d1) + (d2 + d3);
    float a = __builtin_amdgcn_rcpf(1.f + ex2(dot * NSC2));
    float4 acc[8];
    #pragma unroll
    for (int c = 0; c < 8; ++c) {
        float4 vv = vp[c];
        acc[c].x = a * vv.x; acc[c].y = a * vv.y; acc[c].z = a * vv.z; acc[c].w = a * vv.w;
    }
    #pragma unroll
    for (int off = 1; off < 64; off <<= 1) {
        #pragma unroll
        for (int c = 0; c < 8; ++c) {
            acc[c].x += __shfl_xor(acc[c].x, off);
            acc[c].y += __shfl_xor(acc[c].y, off);
            acc[c].z += __shfl_xor(acc[c].z, off);
            acc[c].w += __shfl_xor(acc[c].w, off);
        }
    }
    __shared__ float red[4][32];
    const int wave = tid >> 6, lane = tid & 63;
    if (lane == 0) {
        #pragma unroll
        for (int c = 0; c < 8; ++c) {
            red[wave][c*4+0] = acc[c].x; red[wave][c*4+1] = acc[c].y;
            red[wave][c*4+2] = acc[c].z; red[wave][c*4+3] = acc[c].w;
        }
    }
    __syncthreads();
    if (tid < 32) {
        float t = (red[0][tid] + red[1][tid]) + (red[2][tid] + red[3][tid]);
        if (ms == 0) t += qs[tid];
        P0part[ms * 512 + b * 128 + h * 32 + tid] = t;
    }
}

// ================= fused tail (UNCHANGED, passing) =================
__global__ __launch_bounds__(256) void k_tail(const float* __restrict__ P0part,
                                              const float* __restrict__ W23, const float* __restrict__ b23,
                                              const float* __restrict__ pW, const float* __restrict__ pb,
                                              float* __restrict__ out) {
    const int b = blockIdx.x, tid = threadIdx.x;
    __shared__ float staged[128], pp[128];
    if (tid < 128) {
        float s = 0.f;
        #pragma unroll
        for (int ms = 0; ms < 8; ++ms) s += P0part[ms * 512 + b * 128 + tid];
        staged[tid] = s;
    }
    __syncthreads();
    if (tid < 128) {
        float acc = b23[tid];
        #pragma unroll 8
        for (int k = 0; k < 128; ++k)
            acc = fmaf(staged[k], W23[k * 128 + tid], acc);
        pp[tid] = fmaxf(acc, 0.f) + staged[tid];
    }
    __syncthreads();
    float a = pb[tid];
    #pragma unroll 8
    for (int k = 0; k < 128; ++k)
        a = fmaf(pp[k], pW[k * 256 + tid], a);
    out[b * 256 + tid] = a;
}

extern "C" void kernel_launch(void* const* d_in, const int* in_sizes, int n_in,
                              void* d_out, int out_size, void* d_ws, size_t ws_size,
                              hipStream_t stream) {
    const float* X = (const float*)d_in[0];
    auto W = [&](int i) { return (const float*)d_in[i]; };
    float* ws = (float*)d_ws;

    float* s0 = ws + 0 * SZ;
    float* s1 = ws + 1 * SZ;
    float* s2 = ws + 2 * SZ;
    float* s3 = ws + 3 * SZ;
    HB*    B4  = (HB*)(ws + 4 * SZ);
    HB*    Qb  = B4;
    HB*    Kbf = B4 + SZ;        // head-packed Kh[16][2048][32]
    HB*    Vt  = B4 + 2 * SZ;
    HB*    WtAll = B4 + 3 * SZ;
    auto Wt = [&](int idx) { return (const HB*)(WtAll + (size_t)idx * 16384); };
    float* P0part = s1;

    const int GLM = MN / 32;                 // 256 blocks
    const int attn_blocks = 512;             // qg2*16 + bh
    dim3 wprep_grid(10, 4);
    dim3 pma_grid(Bn * Hh, 8);
    const float* nul = nullptr;

    k_wprep<<<wprep_grid, 256, 0, stream>>>(W(1), W(3), W(5), W(7), W(9), W(11), W(13), W(15),
                                            W(19), W(21), WtAll);

    // ---- SAB layer 0 ----
    k_linm<3,0,0,1><<<GLM, 512, 0, stream>>>(X, nul, Wt(0), W(2), Wt(1), W(4), Wt(2), W(6),
                                             s0, nullptr, Qb, Kbf, Vt);      // Qp0+Qb, Kh, Vt
    // DIAGNOSTIC (R12): attention launched 3x — idempotent (pure overwrite of s2).
    // dur delta vs R11 / 4 = t_attn4. Revert to 1x next round.
    k_attn4<<<attn_blocks, 512, 0, stream>>>(Qb, Kbf, Vt, s2);               // Opart0
    k_attn4<<<attn_blocks, 512, 0, stream>>>(Qb, Kbf, Vt, s2);
    k_attn4<<<attn_blocks, 512, 0, stream>>>(Qb, Kbf, Vt, s2);

    // ---- oproj0 (+X1 in LDS) + QKV1 ----
    k_fused<3,1><<<GLM, 512, 0, stream>>>(s0, s2, Wt(3), W(8),
                                          Wt(4), W(10), Wt(5), W(12), Wt(6), W(14),
                                          s1, nullptr, Qb, Kbf, Vt);         // Qp1+Qb, Kh, Vt
    k_attn4<<<attn_blocks, 512, 0, stream>>>(Qb, Kbf, Vt, s2);               // Opart1
    k_attn4<<<attn_blocks, 512, 0, stream>>>(Qb, Kbf, Vt, s2);
    k_attn4<<<attn_blocks, 512, 0, stream>>>(Qb, Kbf, Vt, s2);

    // ---- oproj1 (+X2 in LDS) + PMA K/V projections (f32 out) ----
    k_fused<2,0><<<GLM, 512, 0, stream>>>(s1, s2, Wt(7), W(16),
                                          Wt(8), W(20), Wt(9), W(22), nullptr, nul,
                                          s0, s3, nullptr, nullptr, nullptr);  // K2, V2

    // ---- PMA attention + tail ----
    k_pma2<<<pma_grid, 256, 0, stream>>>((const float*)d_in[25], W(17), W(18), s0, s3, P0part);
    k_tail<<<Bn, 256, 0, stream>>>(P0part, W(23), W(24), (const float*)d_in[26], (const float*)d_in[27],
                                   (float*)d_out);
}

// Round 13
// 220.657 us; speedup vs baseline: 1.2840x; 1.2840x over previous
//
#include <hip/hip_runtime.h>
#include <hip/hip_bf16.h>

typedef __hip_bfloat16 HB;
typedef __attribute__((ext_vector_type(8))) short short8;
typedef __attribute__((ext_vector_type(4))) short short4v;
typedef __attribute__((ext_vector_type(4))) float f32x4;
typedef __attribute__((ext_vector_type(2))) unsigned int uint2v;
typedef __attribute__((ext_vector_type(4))) unsigned int uint4v;

constexpr int Bn = 4, Nn = 2048, Dm = 128, Hh = 4;
constexpr int MN = Bn * Nn;              // 8192 rows
constexpr size_t SZ = (size_t)MN * Dm;   // 1,048,576 elems per [B,N,128] buffer

static __device__ __forceinline__ short f2bs(float x) {   // RNE
    __hip_bfloat16 h = __float2bfloat16(x);
    return __builtin_bit_cast(short, h);
}
static __device__ __forceinline__ unsigned short f2bh(float x) {  // round-half-up
    return (unsigned short)((__builtin_bit_cast(unsigned int, x) + 0x8000u) >> 16);
}
static __device__ __forceinline__ unsigned int pk2(float lo, float hi) {
    unsigned int a = __builtin_bit_cast(unsigned int, lo) + 0x8000u;
    unsigned int b = __builtin_bit_cast(unsigned int, hi) + 0x8000u;
#if __has_builtin(__builtin_amdgcn_perm)
    return __builtin_amdgcn_perm(b, a, 0x07060302u);
#else
    return (a >> 16) | (b & 0xFFFF0000u);
#endif
}
// fast 2^x (v_exp_f32)
static __device__ __forceinline__ float ex2(float x) {
#if __has_builtin(__builtin_amdgcn_exp2f)
    return __builtin_amdgcn_exp2f(x);
#else
    return exp2f(x);
#endif
}
// sigmoid(s/sqrt(128)) folded: rcp(1 + 2^(s*c)), c = -log2e/sqrt(128)
#define NSC2 (-0.12751884772864078f)

// K bf16 head-packed layout: Kh[bh][n][32dh]
static __device__ __forceinline__ size_t kh_idx(int row, int col) {
    return ((size_t)((row >> 11) * 4 + (col >> 5)) * 2048 + (row & 2047)) * 32 + (col & 31);
}

// ================= weight pre-swizzle (UNCHANGED, passing) =================
__global__ void k_wprep(const float* __restrict__ Wa, const float* __restrict__ Wb,
                        const float* __restrict__ Wc, const float* __restrict__ Wd,
                        const float* __restrict__ We, const float* __restrict__ Wf,
                        const float* __restrict__ Wg, const float* __restrict__ Wh,
                        const float* __restrict__ Wi, const float* __restrict__ Wj,
                        HB* __restrict__ WtAll) {
    const float* src;
    switch (blockIdx.x) {
        case 0: src = Wa; break; case 1: src = Wb; break;
        case 2: src = Wc; break; case 3: src = Wd; break;
        case 4: src = We; break; case 5: src = Wf; break;
        case 6: src = Wg; break; case 7: src = Wh; break;
        case 8: src = Wi; break; default: src = Wj; break;
    }
    HB* dst = WtAll + (size_t)blockIdx.x * 16384;
    #pragma unroll
    for (int it = 0; it < 2; ++it) {
        int idx = blockIdx.y * 512 + it * 256 + threadIdx.x;   // 0..2047
        int g = idx >> 7, c = idx & 127;
        short8 p;
        #pragma unroll
        for (int j = 0; j < 8; ++j) p[j] = f2bs(src[(size_t)(g * 8 + j) * 128 + c]);
        *(short8*)((short*)dst + (size_t)idx * 8) = p;
    }
}

// ================= high-occupancy MFMA linear =================
// block 256 thr = 4 waves; wave w: one 16-row x 16-col tile per weight.
// grid (M/16, 2): blockIdx.y*64 + w*16 = col base. 1024 blocks -> 4 blocks/CU, 4 waves/SIMD.
// ABF: A is packed bf16 [row][128]. OUTB: s0 epilogue = relu+residual -> Xb bf16 only.
// FUSE: s0 -> C0 f32 + Qb bf16; s1 -> Kh bf16; s2 -> Vt bf16 (pi-permuted).
template<int NW, int NEXTRA, int FUSE, int ABF, int OUTB>
__global__ __launch_bounds__(256) void k_lin2(
        const void* __restrict__ Av, const float* __restrict__ extra,
        const HB* __restrict__ Wt0, const float* __restrict__ b0,
        const HB* __restrict__ Wt1, const float* __restrict__ b1,
        const HB* __restrict__ Wt2, const float* __restrict__ b2,
        float* __restrict__ C0, float* __restrict__ C1,
        HB* __restrict__ Xb, HB* __restrict__ Qb, HB* __restrict__ Kb, HB* __restrict__ Vt) {
    const int tid = threadIdx.x;
    const int w = tid >> 6, lane = tid & 63, l15 = lane & 15, quad = lane >> 4;
    const int row0 = blockIdx.x * 16;
    const int col = blockIdx.y * 64 + w * 16 + l15;
    const float* Af = (const float*)Av;

    // A-frags: A[row=l15][k=quad*8+j] packed bf16
    short8 af[4];
    if (ABF) {
        const short* ab = (const short*)Av + (size_t)(row0 + l15) * 128 + quad * 8;
        #pragma unroll
        for (int kc = 0; kc < 4; ++kc)
            af[kc] = *(const short8*)(ab + kc * 32);
    } else {
        #pragma unroll
        for (int kc = 0; kc < 4; ++kc) {
            const float* ap = Af + (size_t)(row0 + l15) * 128 + kc * 32 + quad * 8;
            float4 x0 = *(const float4*)ap;
            float4 x1 = *(const float4*)(ap + 4);
            if (NEXTRA) {
                const float* ep = extra + (size_t)(row0 + l15) * 128 + kc * 32 + quad * 8;
                float4 e0 = *(const float4*)ep, e1 = *(const float4*)(ep + 4);
                x0.x += e0.x; x0.y += e0.y; x0.z += e0.z; x0.w += e0.w;
                x1.x += e1.x; x1.y += e1.y; x1.z += e1.z; x1.w += e1.w;
            }
            uint4v u;
            u[0] = pk2(x0.x, x0.y); u[1] = pk2(x0.z, x0.w);
            u[2] = pk2(x1.x, x1.y); u[3] = pk2(x1.z, x1.w);
            af[kc] = __builtin_bit_cast(short8, u);
        }
    }

    f32x4 zero = {0.f, 0.f, 0.f, 0.f};
    #pragma unroll
    for (int s = 0; s < NW; ++s) {
        const HB* Wt = (s == 0) ? Wt0 : (s == 1) ? Wt1 : Wt2;
        const float* bs = (s == 0) ? b0 : (s == 1) ? b1 : b2;
        f32x4 acc = zero;
        #pragma unroll
        for (int kc = 0; kc < 4; ++kc) {
            short8 bf = *(const short8*)((const short*)Wt + ((size_t)(kc * 4 + quad) * 128 + col) * 8);
            acc = __builtin_amdgcn_mfma_f32_16x16x32_bf16(af[kc], bf, acc, 0, 0, 0);
        }
        float bb = bs[col];
        if (s == 0) {
            if (OUTB) {                    // oproj: Xb = bf16(staged + relu(gemm+b))
                #pragma unroll
                for (int r = 0; r < 4; ++r) {
                    int row = row0 + quad * 4 + r;
                    float st = Af[(size_t)row * 128 + col];
                    if (NEXTRA) st += extra[(size_t)row * 128 + col];
                    float v = fmaxf(acc[r] + bb, 0.f) + st;
                    ((unsigned short*)Xb)[(size_t)row * 128 + col] = f2bh(v);
                }
            } else if (FUSE) {             // Q: f32 + bf16
                #pragma unroll
                for (int r = 0; r < 4; ++r) {
                    int row = row0 + quad * 4 + r;
                    float v = acc[r] + bb;
                    C0[(size_t)row * 128 + col] = v;
                    ((unsigned short*)Qb)[(size_t)row * 128 + col] = f2bh(v);
                }
            } else {                       // plain f32
                #pragma unroll
                for (int r = 0; r < 4; ++r) {
                    int row = row0 + quad * 4 + r;
                    C0[(size_t)row * 128 + col] = acc[r] + bb;
                }
            }
        } else if (s == 1) {
            if (FUSE) {                    // K -> head-packed bf16 Kh[bh][n][32]
                #pragma unroll
                for (int r = 0; r < 4; ++r) {
                    int row = row0 + quad * 4 + r;
                    ((unsigned short*)Kb)[kh_idx(row, col)] = f2bh(acc[r] + bb);
                }
            } else {
                #pragma unroll
                for (int r = 0; r < 4; ++r) {
                    int row = row0 + quad * 4 + r;
                    C1[(size_t)row * 128 + col] = acc[r] + bb;
                }
            }
        } else {                           // V -> Vt bf16 [bh][dh][2048], pi-permuted n
            int b_ = row0 >> 11;
            int mloc = (row0 + quad * 4) & 2047;
            int slotb = (mloc & ~31) + (((mloc & 15) >> 2) << 3) + (((mloc >> 4) & 1) << 2);
            int h_ = col >> 5, dh = col & 31;
            uint2v pv;
            pv[0] = pk2(acc[0] + bb, acc[1] + bb);
            pv[1] = pk2(acc[2] + bb, acc[3] + bb);
            *(short4v*)((short*)Vt + ((size_t)((b_ * 4 + h_) * 32 + dh)) * 2048 + slotb)
                = __builtin_bit_cast(short4v, pv);
        }
    }
}

// ================= MFMA sigmoid attention v5 (UNCHANGED, near trans-roofline) =================
__global__ __launch_bounds__(512, 4) void k_attn4(const HB* __restrict__ Qb, const HB* __restrict__ Kbf,
                                                  const HB* __restrict__ Vt, float* __restrict__ Opart) {
    const int tid = threadIdx.x;
    const int w = tid >> 6, lane = tid & 63, l15 = lane & 15, quad = lane >> 4;
    const int bh = blockIdx.x & 15, qg2 = blockIdx.x >> 4;
    const int b = bh >> 2, h = bh & 3;
    const int q0row = qg2 * 64;

    __shared__ float ldsacc[8][64][36];

    short8 aq[4];
    {
        const short* qp = (const short*)Qb + (size_t)(b * Nn + q0row) * 128 + h * 32 + quad * 8;
        #pragma unroll
        for (int qa = 0; qa < 4; ++qa)
            aq[qa] = *(const short8*)(qp + (size_t)(qa * 16 + l15) * 128);
    }

    f32x4 zero = {0.f, 0.f, 0.f, 0.f};
    f32x4 o[4][2];
    #pragma unroll
    for (int qa = 0; qa < 4; ++qa) { o[qa][0] = zero; o[qa][1] = zero; }

    const short* Kb = (const short*)Kbf + (size_t)bh * Nn * 32;   // head-packed
    const short* Vb = (const short*)Vt + (size_t)bh * 32 * Nn;

    for (int m0 = w * 256; m0 < w * 256 + 256; m0 += 64) {
        short8 kb[4];
        #pragma unroll
        for (int mc = 0; mc < 4; ++mc)
            kb[mc] = *(const short8*)(Kb + (size_t)(m0 + mc * 16 + l15) * 32 + quad * 8);
        short8 vf[2][2];
        #pragma unroll
        for (int t = 0; t < 2; ++t)
            #pragma unroll
            for (int u = 0; u < 2; ++u)
                vf[t][u] = *(const short8*)(Vb + (size_t)(t * 16 + l15) * Nn + m0 + u * 32 + quad * 8);

        #pragma unroll
        for (int qa = 0; qa < 4; ++qa) {
            f32x4 s[4];
            #pragma unroll
            for (int mc = 0; mc < 4; ++mc)
                s[mc] = __builtin_amdgcn_mfma_f32_16x16x32_bf16(kb[mc], aq[qa], zero, 0, 0, 0);
            #pragma unroll
            for (int u = 0; u < 2; ++u) {
                f32x4 lo = s[2 * u], hi = s[2 * u + 1];
                float p0 = __builtin_amdgcn_rcpf(1.f + ex2(lo[0] * NSC2));
                float p1 = __builtin_amdgcn_rcpf(1.f + ex2(lo[1] * NSC2));
                float p2 = __builtin_amdgcn_rcpf(1.f + ex2(lo[2] * NSC2));
                float p3 = __builtin_amdgcn_rcpf(1.f + ex2(lo[3] * NSC2));
                float p4 = __builtin_amdgcn_rcpf(1.f + ex2(hi[0] * NSC2));
                float p5 = __builtin_amdgcn_rcpf(1.f + ex2(hi[1] * NSC2));
                float p6 = __builtin_amdgcn_rcpf(1.f + ex2(hi[2] * NSC2));
                float p7 = __builtin_amdgcn_rcpf(1.f + ex2(hi[3] * NSC2));
                uint4v pu;
                pu[0] = pk2(p0, p1); pu[1] = pk2(p2, p3);
                pu[2] = pk2(p4, p5); pu[3] = pk2(p6, p7);
                short8 pf = __builtin_bit_cast(short8, pu);
                #pragma unroll
                for (int t = 0; t < 2; ++t)
                    o[qa][t] = __builtin_amdgcn_mfma_f32_16x16x32_bf16(vf[t][u], pf, o[qa][t], 0, 0, 0);
            }
        }
    }

    #pragma unroll
    for (int qa = 0; qa < 4; ++qa)
        #pragma unroll
        for (int t = 0; t < 2; ++t)
            *(f32x4*)&ldsacc[w][qa * 16 + l15][t * 16 + quad * 4] = o[qa][t];
    __syncthreads();
    const int row = tid >> 3, cc = (tid & 7) * 4;
    f32x4 sum = zero;
    #pragma unroll
    for (int ww = 0; ww < 8; ++ww) {
        f32x4 r = *(f32x4*)&ldsacc[ww][row][cc];
        sum += r;
    }
    *(f32x4*)(Opart + (size_t)(b * Nn + q0row + row) * 128 + h * 32 + cc) = sum;
}

// ================= PMA attention (UNCHANGED, passing) =================
__global__ void k_pma2(const float* __restrict__ S, const float* __restrict__ Wq, const float* __restrict__ bq,
                       const float* __restrict__ Kp, const float* __restrict__ Vp,
                       float* __restrict__ P0part) {
    const int bh = blockIdx.x, b = bh >> 2, h = bh & 3;
    const int ms = blockIdx.y;
    const int tid = threadIdx.x;
    __shared__ float4 qs4[8];
    float* qs = (float*)qs4;
    if (tid < 32) {
        float a = bq[h * 32 + tid];
        for (int k = 0; k < 128; ++k)
            a = fmaf(S[k], Wq[k * Dm + h * 32 + tid], a);
        qs[tid] = a;
    }
    __syncthreads();

    float4 q[8];
    #pragma unroll
    for (int i = 0; i < 8; ++i) q[i] = qs4[i];

    const size_t base = (size_t)b * Nn * Dm + h * 32;
    const int m = blockIdx.y * 256 + tid;

    const float4* kp = (const float4*)(Kp + base + (size_t)m * Dm);
    const float4* vp = (const float4*)(Vp + base + (size_t)m * Dm);
    float d0 = 0.f, d1 = 0.f, d2 = 0.f, d3 = 0.f;
    #pragma unroll
    for (int c = 0; c < 8; c += 4) {
        float4 k0 = kp[c+0], k1 = kp[c+1], k2 = kp[c+2], k3 = kp[c+3];
        d0 += q[c+0].x*k0.x + q[c+0].y*k0.y + q[c+0].z*k0.z + q[c+0].w*k0.w;
        d1 += q[c+1].x*k1.x + q[c+1].y*k1.y + q[c+1].z*k1.z + q[c+1].w*k1.w;
        d2 += q[c+2].x*k2.x + q[c+2].y*k2.y + q[c+2].z*k2.z + q[c+2].w*k2.w;
        d3 += q[c+3].x*k3.x + q[c+3].y*k3.y + q[c+3].z*k3.z + q[c+3].w*k3.w;
    }
    float dot = (d0 + d1) + (d2 + d3);
    float a = __builtin_amdgcn_rcpf(1.f + ex2(dot * NSC2));
    float4 acc[8];
    #pragma unroll
    for (int c = 0; c < 8; ++c) {
        float4 vv = vp[c];
        acc[c].x = a * vv.x; acc[c].y = a * vv.y; acc[c].z = a * vv.z; acc[c].w = a * vv.w;
    }
    #pragma unroll
    for (int off = 1; off < 64; off <<= 1) {
        #pragma unroll
        for (int c = 0; c < 8; ++c) {
            acc[c].x += __shfl_xor(acc[c].x, off);
            acc[c].y += __shfl_xor(acc[c].y, off);
            acc[c].z += __shfl_xor(acc[c].z, off);
            acc[c].w += __shfl_xor(acc[c].w, off);
        }
    }
    __shared__ float red[4][32];
    const int wave = tid >> 6, lane = tid & 63;
    if (lane == 0) {
        #pragma unroll
        for (int c = 0; c < 8; ++c) {
            red[wave][c*4+0] = acc[c].x; red[wave][c*4+1] = acc[c].y;
            red[wave][c*4+2] = acc[c].z; red[wave][c*4+3] = acc[c].w;
        }
    }
    __syncthreads();
    if (tid < 32) {
        float t = (red[0][tid] + red[1][tid]) + (red[2][tid] + red[3][tid]);
        if (blockIdx.y == 0) t += qs[tid];
        P0part[blockIdx.y * 512 + b * 128 + h * 32 + tid] = t;
    }
}

// ================= fused tail (UNCHANGED, passing) =================
__global__ __launch_bounds__(256) void k_tail(const float* __restrict__ P0part,
                                              const float* __restrict__ W23, const float* __restrict__ b23,
                                              const float* __restrict__ pW, const float* __restrict__ pb,
                                              float* __restrict__ out) {
    const int b = blockIdx.x, tid = threadIdx.x;
    __shared__ float staged[128], pp[128];
    if (tid < 128) {
        float s = 0.f;
        #pragma unroll
        for (int ms = 0; ms < 8; ++ms) s += P0part[ms * 512 + b * 128 + tid];
        staged[tid] = s;
    }
    __syncthreads();
    if (tid < 128) {
        float acc = b23[tid];
        #pragma unroll 8
        for (int k = 0; k < 128; ++k)
            acc = fmaf(staged[k], W23[k * 128 + tid], acc);
        pp[tid] = fmaxf(acc, 0.f) + staged[tid];
    }
    __syncthreads();
    float a = pb[tid];
    #pragma unroll 8
    for (int k = 0; k < 128; ++k)
        a = fmaf(pp[k], pW[k * 256 + tid], a);
    out[b * 256 + tid] = a;
}

extern "C" void kernel_launch(void* const* d_in, const int* in_sizes, int n_in,
                              void* d_out, int out_size, void* d_ws, size_t ws_size,
                              hipStream_t stream) {
    const float* X = (const float*)d_in[0];
    auto W = [&](int i) { return (const float*)d_in[i]; };
    float* ws = (float*)d_ws;

    // f32 slots: s0: Qp0 -> K2   s1: Qp1 -> P0part   s2: Opart   s3: V2
    // bf16 region: Qb, Kh, Vt, Xb (each SZ elems), WtAll (320 KB)
    float* s0 = ws + 0 * SZ;
    float* s1 = ws + 1 * SZ;
    float* s2 = ws + 2 * SZ;
    float* s3 = ws + 3 * SZ;
    HB*    B4  = (HB*)(ws + 4 * SZ);
    HB*    Qb  = B4;
    HB*    Kbf = B4 + SZ;        // head-packed Kh[16][2048][32]
    HB*    Vt  = B4 + 2 * SZ;
    HB*    Xb  = B4 + 3 * SZ;
    HB*    WtAll = B4 + 4 * SZ;
    auto Wt = [&](int idx) { return (const HB*)(WtAll + (size_t)idx * 16384); };
    float* P0part = s1;

    dim3 lin_grid(MN / 16, 2);               // 1024 blocks, 256 thr
    const int attn_blocks = 512;             // qg2*16 + bh
    dim3 wprep_grid(10, 4);
    dim3 pma_grid(Bn * Hh, 8);
    const float* nul = nullptr;
    HB* nulh = nullptr;

    k_wprep<<<wprep_grid, 256, 0, stream>>>(W(1), W(3), W(5), W(7), W(9), W(11), W(13), W(15),
                                            W(19), W(21), WtAll);

    // ---- SAB layer 0: QKV from X (f32 A) ----
    k_lin2<3,0,1,0,0><<<lin_grid, 256, 0, stream>>>(X, nul, Wt(0), W(2), Wt(1), W(4), Wt(2), W(6),
                                                    s0, nullptr, nulh, Qb, Kbf, Vt);
    k_attn4<<<attn_blocks, 512, 0, stream>>>(Qb, Kbf, Vt, s2);               // Opart0
    // ---- oproj0: Xb = bf16(Qp0 + Opart + relu-FFN) ----
    k_lin2<1,1,0,0,1><<<lin_grid, 256, 0, stream>>>(s0, s2, Wt(3), W(8), nullptr, nul, nullptr, nul,
                                                    nullptr, nullptr, Xb, nulh, nulh, nulh);

    // ---- SAB layer 1: QKV from Xb (bf16 A) ----
    k_lin2<3,0,1,1,0><<<lin_grid, 256, 0, stream>>>(Xb, nul, Wt(4), W(10), Wt(5), W(12), Wt(6), W(14),
                                                    s1, nullptr, nulh, Qb, Kbf, Vt);
    k_attn4<<<attn_blocks, 512, 0, stream>>>(Qb, Kbf, Vt, s2);               // Opart1
    // ---- oproj1: Xb = bf16(Qp1 + Opart + relu-FFN) ----
    k_lin2<1,1,0,0,1><<<lin_grid, 256, 0, stream>>>(s1, s2, Wt(7), W(16), nullptr, nul, nullptr, nul,
                                                    nullptr, nullptr, Xb, nulh, nulh, nulh);

    // ---- PMA K/V projections from Xb (f32 out) ----
    k_lin2<2,0,0,1,0><<<lin_grid, 256, 0, stream>>>(Xb, nul, Wt(8), W(20), Wt(9), W(22), nullptr, nul,
                                                    s0, s3, nulh, nulh, nulh, nulh);

    // ---- PMA attention + tail ----
    k_pma2<<<pma_grid, 256, 0, stream>>>((const float*)d_in[25], W(17), W(18), s0, s3, P0part);
    k_tail<<<Bn, 256, 0, stream>>>(P0part, W(23), W(24), (const float*)d_in[26], (const float*)d_in[27],
                                   (float*)d_out);
}

// Round 15
// 211.000 us; speedup vs baseline: 1.3427x; 1.0458x over previous
//
#include <hip/hip_runtime.h>
#include <hip/hip_bf16.h>

typedef __hip_bfloat16 HB;
typedef __attribute__((ext_vector_type(8))) short short8;
typedef __attribute__((ext_vector_type(4))) short short4v;
typedef __attribute__((ext_vector_type(4))) float f32x4;
typedef __attribute__((ext_vector_type(2))) unsigned int uint2v;
typedef __attribute__((ext_vector_type(4))) unsigned int uint4v;

constexpr int Bn = 4, Nn = 2048, Dm = 128, Hh = 4;
constexpr int MN = Bn * Nn;              // 8192 rows
constexpr size_t SZ = (size_t)MN * Dm;   // 1,048,576 elems per [B,N,128] buffer

static __device__ __forceinline__ short f2bs(float x) {   // RNE
    __hip_bfloat16 h = __float2bfloat16(x);
    return __builtin_bit_cast(short, h);
}
static __device__ __forceinline__ unsigned short f2bh(float x) {  // round-half-up
    return (unsigned short)((__builtin_bit_cast(unsigned int, x) + 0x8000u) >> 16);
}
static __device__ __forceinline__ unsigned int pk2(float lo, float hi) {
    unsigned int a = __builtin_bit_cast(unsigned int, lo) + 0x8000u;
    unsigned int b = __builtin_bit_cast(unsigned int, hi) + 0x8000u;
#if __has_builtin(__builtin_amdgcn_perm)
    return __builtin_amdgcn_perm(b, a, 0x07060302u);
#else
    return (a >> 16) | (b & 0xFFFF0000u);
#endif
}
static __device__ __forceinline__ float ex2(float x) {
#if __has_builtin(__builtin_amdgcn_exp2f)
    return __builtin_amdgcn_exp2f(x);
#else
    return exp2f(x);
#endif
}
#define NSC2 (-0.12751884772864078f)   // -log2e/sqrt(128)

// K bf16 head-packed layout: Kh[bh][n][32dh]
static __device__ __forceinline__ size_t kh_idx(int row, int col) {
    return ((size_t)((row >> 11) * 4 + (col >> 5)) * 2048 + (row & 2047)) * 32 + (col & 31);
}

// ================= weight pre-swizzle (UNCHANGED, passing) =================
__global__ void k_wprep(const float* __restrict__ Wa, const float* __restrict__ Wb,
                        const float* __restrict__ Wc, const float* __restrict__ Wd,
                        const float* __restrict__ We, const float* __restrict__ Wf,
                        const float* __restrict__ Wg, const float* __restrict__ Wh,
                        const float* __restrict__ Wi, const float* __restrict__ Wj,
                        HB* __restrict__ WtAll) {
    const float* src;
    switch (blockIdx.x) {
        case 0: src = Wa; break; case 1: src = Wb; break;
        case 2: src = Wc; break; case 3: src = Wd; break;
        case 4: src = We; break; case 5: src = Wf; break;
        case 6: src = Wg; break; case 7: src = Wh; break;
        case 8: src = Wi; break; default: src = Wj; break;
    }
    HB* dst = WtAll + (size_t)blockIdx.x * 16384;
    #pragma unroll
    for (int it = 0; it < 2; ++it) {
        int idx = blockIdx.y * 512 + it * 256 + threadIdx.x;   // 0..2047
        int g = idx >> 7, c = idx & 127;
        short8 p;
        #pragma unroll
        for (int j = 0; j < 8; ++j) p[j] = f2bs(src[(size_t)(g * 8 + j) * 128 + c]);
        *(short8*)((short*)dst + (size_t)idx * 8) = p;
    }
}

// ================= QKV projection, high-occupancy (16 rows/block, 8 col-waves) =================
// grid 512 x 512 thr. FUSE outputs: C0 f32 + Qb bf16; Kh bf16; Vt bf16 (pi-permuted).
__global__ __launch_bounds__(512) void k_qkv(
        const float* __restrict__ A,
        const HB* __restrict__ Wt0, const float* __restrict__ b0,
        const HB* __restrict__ Wt1, const float* __restrict__ b1,
        const HB* __restrict__ Wt2, const float* __restrict__ b2,
        float* __restrict__ C0, HB* __restrict__ Qb, HB* __restrict__ Kb, HB* __restrict__ Vt) {
    const int tid = threadIdx.x;
    const int w = tid >> 6, lane = tid & 63, l15 = lane & 15, quad = lane >> 4;
    const int row0 = blockIdx.x * 16;
    const int col = w * 16 + l15;

    short8 af[4];
    #pragma unroll
    for (int kc = 0; kc < 4; ++kc) {
        const float* ap = A + (size_t)(row0 + l15) * 128 + kc * 32 + quad * 8;
        float4 x0 = *(const float4*)ap, x1 = *(const float4*)(ap + 4);
        uint4v u;
        u[0] = pk2(x0.x, x0.y); u[1] = pk2(x0.z, x0.w);
        u[2] = pk2(x1.x, x1.y); u[3] = pk2(x1.z, x1.w);
        af[kc] = __builtin_bit_cast(short8, u);
    }

    f32x4 zero = {0.f, 0.f, 0.f, 0.f};
    #pragma unroll
    for (int s = 0; s < 3; ++s) {
        const HB* Wt = (s == 0) ? Wt0 : (s == 1) ? Wt1 : Wt2;
        const float* bs = (s == 0) ? b0 : (s == 1) ? b1 : b2;
        f32x4 acc = zero;
        #pragma unroll
        for (int kc = 0; kc < 4; ++kc) {
            short8 bf = *(const short8*)((const short*)Wt + ((size_t)(kc * 4 + quad) * 128 + col) * 8);
            acc = __builtin_amdgcn_mfma_f32_16x16x32_bf16(af[kc], bf, acc, 0, 0, 0);
        }
        float bb = bs[col];
        if (s == 0) {
            #pragma unroll
            for (int r = 0; r < 4; ++r) {
                int row = row0 + quad * 4 + r;
                float v = acc[r] + bb;
                C0[(size_t)row * 128 + col] = v;
                ((unsigned short*)Qb)[(size_t)row * 128 + col] = f2bh(v);
            }
        } else if (s == 1) {
            #pragma unroll
            for (int r = 0; r < 4; ++r)
                ((unsigned short*)Kb)[kh_idx(row0 + quad * 4 + r, col)] = f2bh(acc[r] + bb);
        } else {
            int b_ = row0 >> 11;
            int mloc = (row0 + quad * 4) & 2047;
            int slotb = (mloc & ~31) + (((mloc & 15) >> 2) << 3) + (((mloc >> 4) & 1) << 2);
            int h_ = col >> 5, dh = col & 31;
            uint2v pv;
            pv[0] = pk2(acc[0] + bb, acc[1] + bb);
            pv[1] = pk2(acc[2] + bb, acc[3] + bb);
            *(short4v*)((short*)Vt + ((size_t)((b_ * 4 + h_) * 32 + dh)) * 2048 + slotb)
                = __builtin_bit_cast(short4v, pv);
        }
    }
}

// ================= fused oproj + downstream GEMMs, high-occupancy =================
// grid 512 x 512 thr; 16 rows/block; X tile (16x132 f32) in LDS only.
template<int NQKV, int FUSE>
__global__ __launch_bounds__(512) void k_fused2(
        const float* __restrict__ A, const float* __restrict__ extra,
        const HB* __restrict__ WtO, const float* __restrict__ bO,
        const HB* __restrict__ Wt0, const float* __restrict__ b0,
        const HB* __restrict__ Wt1, const float* __restrict__ b1,
        const HB* __restrict__ Wt2, const float* __restrict__ b2,
        float* __restrict__ C0, float* __restrict__ C1,
        HB* __restrict__ Qb, HB* __restrict__ Kb, HB* __restrict__ Vt) {
    const int tid = threadIdx.x;
    const int w = tid >> 6, lane = tid & 63, l15 = lane & 15, quad = lane >> 4;
    const int row0 = blockIdx.x * 16;
    const int col = w * 16 + l15;

    __shared__ float xs[16 * 132];

    f32x4 zero = {0.f, 0.f, 0.f, 0.f};

    short8 af[4];
    #pragma unroll
    for (int kc = 0; kc < 4; ++kc) {
        const float* ap = A + (size_t)(row0 + l15) * 128 + kc * 32 + quad * 8;
        float4 x0 = *(const float4*)ap, x1 = *(const float4*)(ap + 4);
        const float* ep = extra + (size_t)(row0 + l15) * 128 + kc * 32 + quad * 8;
        float4 e0 = *(const float4*)ep, e1 = *(const float4*)(ep + 4);
        x0.x += e0.x; x0.y += e0.y; x0.z += e0.z; x0.w += e0.w;
        x1.x += e1.x; x1.y += e1.y; x1.z += e1.z; x1.w += e1.w;
        uint4v u;
        u[0] = pk2(x0.x, x0.y); u[1] = pk2(x0.z, x0.w);
        u[2] = pk2(x1.x, x1.y); u[3] = pk2(x1.z, x1.w);
        af[kc] = __builtin_bit_cast(short8, u);
    }

    // O-projection -> X tile in LDS
    {
        f32x4 acc = zero;
        #pragma unroll
        for (int kc = 0; kc < 4; ++kc) {
            short8 bf = *(const short8*)((const short*)WtO + ((size_t)(kc * 4 + quad) * 128 + col) * 8);
            acc = __builtin_amdgcn_mfma_f32_16x16x32_bf16(af[kc], bf, acc, 0, 0, 0);
        }
        float bb = bO[col];
        #pragma unroll
        for (int r = 0; r < 4; ++r) {
            int row = row0 + quad * 4 + r;
            float st = A[(size_t)row * 128 + col] + extra[(size_t)row * 128 + col];
            xs[(quad * 4 + r) * 132 + col] = fmaxf(acc[r] + bb, 0.f) + st;
        }
    }
    __syncthreads();

    short8 a2[4];
    {
        const float* xrow = xs + (size_t)l15 * 132;
        #pragma unroll
        for (int kc = 0; kc < 4; ++kc) {
            f32x4 x0 = *(const f32x4*)(xrow + kc * 32 + quad * 8);
            f32x4 x1 = *(const f32x4*)(xrow + kc * 32 + quad * 8 + 4);
            uint4v u;
            u[0] = pk2(x0[0], x0[1]); u[1] = pk2(x0[2], x0[3]);
            u[2] = pk2(x1[0], x1[1]); u[3] = pk2(x1[2], x1[3]);
            a2[kc] = __builtin_bit_cast(short8, u);
        }
    }

    #pragma unroll
    for (int s = 0; s < NQKV; ++s) {
        const HB* Wt = (s == 0) ? Wt0 : (s == 1) ? Wt1 : Wt2;
        const float* bs = (s == 0) ? b0 : (s == 1) ? b1 : b2;
        f32x4 acc = zero;
        #pragma unroll
        for (int kc = 0; kc < 4; ++kc) {
            short8 bf = *(const short8*)((const short*)Wt + ((size_t)(kc * 4 + quad) * 128 + col) * 8);
            acc = __builtin_amdgcn_mfma_f32_16x16x32_bf16(a2[kc], bf, acc, 0, 0, 0);
        }
        float bb = bs[col];
        if (s == 0) {
            #pragma unroll
            for (int r = 0; r < 4; ++r) {
                int row = row0 + quad * 4 + r;
                float v = acc[r] + bb;
                C0[(size_t)row * 128 + col] = v;
                if (FUSE) ((unsigned short*)Qb)[(size_t)row * 128 + col] = f2bh(v);
            }
        } else if (s == 1) {
            if (FUSE) {
                #pragma unroll
                for (int r = 0; r < 4; ++r)
                    ((unsigned short*)Kb)[kh_idx(row0 + quad * 4 + r, col)] = f2bh(acc[r] + bb);
            } else {
                #pragma unroll
                for (int r = 0; r < 4; ++r) {
                    int row = row0 + quad * 4 + r;
                    C1[(size_t)row * 128 + col] = acc[r] + bb;
                }
            }
        } else {
            int b_ = row0 >> 11;
            int mloc = (row0 + quad * 4) & 2047;
            int slotb = (mloc & ~31) + (((mloc & 15) >> 2) << 3) + (((mloc >> 4) & 1) << 2);
            int h_ = col >> 5, dh = col & 31;
            uint2v pv;
            pv[0] = pk2(acc[0] + bb, acc[1] + bb);
            pv[1] = pk2(acc[2] + bb, acc[3] + bb);
            *(short4v*)((short*)Vt + ((size_t)((b_ * 4 + h_) * 32 + dh)) * 2048 + slotb)
                = __builtin_bit_cast(short4v, pv);
        }
    }
}

// ================= MFMA sigmoid attention v5 (UNCHANGED from R11, passing) =================
__global__ __launch_bounds__(512, 4) void k_attn4(const HB* __restrict__ Qb, const HB* __restrict__ Kbf,
                                                  const HB* __restrict__ Vt, float* __restrict__ Opart) {
    const int tid = threadIdx.x;
    const int w = tid >> 6, lane = tid & 63, l15 = lane & 15, quad = lane >> 4;
    const int bh = blockIdx.x & 15, qg2 = blockIdx.x >> 4;
    const int b = bh >> 2, h = bh & 3;
    const int q0row = qg2 * 64;

    __shared__ float ldsacc[8][64][36];

    short8 aq[4];
    {
        const short* qp = (const short*)Qb + (size_t)(b * Nn + q0row) * 128 + h * 32 + quad * 8;
        #pragma unroll
        for (int qa = 0; qa < 4; ++qa)
            aq[qa] = *(const short8*)(qp + (size_t)(qa * 16 + l15) * 128);
    }

    f32x4 zero = {0.f, 0.f, 0.f, 0.f};
    f32x4 o[4][2];
    #pragma unroll
    for (int qa = 0; qa < 4; ++qa) { o[qa][0] = zero; o[qa][1] = zero; }

    const short* Kb = (const short*)Kbf + (size_t)bh * Nn * 32;   // head-packed
    const short* Vb = (const short*)Vt + (size_t)bh * 32 * Nn;

    for (int m0 = w * 256; m0 < w * 256 + 256; m0 += 64) {
        short8 kb[4];
        #pragma unroll
        for (int mc = 0; mc < 4; ++mc)
            kb[mc] = *(const short8*)(Kb + (size_t)(m0 + mc * 16 + l15) * 32 + quad * 8);
        short8 vf[2][2];
        #pragma unroll
        for (int t = 0; t < 2; ++t)
            #pragma unroll
            for (int u = 0; u < 2; ++u)
                vf[t][u] = *(const short8*)(Vb + (size_t)(t * 16 + l15) * Nn + m0 + u * 32 + quad * 8);

        #pragma unroll
        for (int qa = 0; qa < 4; ++qa) {
            f32x4 s[4];
            #pragma unroll
            for (int mc = 0; mc < 4; ++mc)
                s[mc] = __builtin_amdgcn_mfma_f32_16x16x32_bf16(kb[mc], aq[qa], zero, 0, 0, 0);
            #pragma unroll
            for (int u = 0; u < 2; ++u) {
                f32x4 lo = s[2 * u], hi = s[2 * u + 1];
                float p0 = __builtin_amdgcn_rcpf(1.f + ex2(lo[0] * NSC2));
                float p1 = __builtin_amdgcn_rcpf(1.f + ex2(lo[1] * NSC2));
                float p2 = __builtin_amdgcn_rcpf(1.f + ex2(lo[2] * NSC2));
                float p3 = __builtin_amdgcn_rcpf(1.f + ex2(lo[3] * NSC2));
                float p4 = __builtin_amdgcn_rcpf(1.f + ex2(hi[0] * NSC2));
                float p5 = __builtin_amdgcn_rcpf(1.f + ex2(hi[1] * NSC2));
                float p6 = __builtin_amdgcn_rcpf(1.f + ex2(hi[2] * NSC2));
                float p7 = __builtin_amdgcn_rcpf(1.f + ex2(hi[3] * NSC2));
                uint4v pu;
                pu[0] = pk2(p0, p1); pu[1] = pk2(p2, p3);
                pu[2] = pk2(p4, p5); pu[3] = pk2(p6, p7);
                short8 pf = __builtin_bit_cast(short8, pu);
                #pragma unroll
                for (int t = 0; t < 2; ++t)
                    o[qa][t] = __builtin_amdgcn_mfma_f32_16x16x32_bf16(vf[t][u], pf, o[qa][t], 0, 0, 0);
            }
        }
    }

    #pragma unroll
    for (int qa = 0; qa < 4; ++qa)
        #pragma unroll
        for (int t = 0; t < 2; ++t)
            *(f32x4*)&ldsacc[w][qa * 16 + l15][t * 16 + quad * 4] = o[qa][t];
    __syncthreads();
    const int row = tid >> 3, cc = (tid & 7) * 4;
    f32x4 sum = zero;
    #pragma unroll
    for (int ww = 0; ww < 8; ++ww)
        sum += *(f32x4*)&ldsacc[ww][row][cc];
    *(f32x4*)(Opart + (size_t)(b * Nn + q0row + row) * 128 + h * 32 + cc) = sum;
}

// ================= PMA attention (UNCHANGED from R11, passing) =================
__global__ void k_pma2(const float* __restrict__ S, const float* __restrict__ Wq, const float* __restrict__ bq,
                       const float* __restrict__ Kp, const float* __restrict__ Vp,
                       float* __restrict__ P0part) {
    const int bh = blockIdx.x, b = bh >> 2, h = bh & 3;
    const int tid = threadIdx.x;
    __shared__ float4 qs4[8];
    float* qs = (float*)qs4;
    if (tid < 32) {
        float a = bq[h * 32 + tid];
        for (int k = 0; k < 128; ++k)
            a = fmaf(S[k], Wq[k * Dm + h * 32 + tid], a);
        qs[tid] = a;
    }
    __syncthreads();

    float4 q[8];
    #pragma unroll
    for (int i = 0; i < 8; ++i) q[i] = qs4[i];

    const size_t base = (size_t)b * Nn * Dm + h * 32;
    const int m = blockIdx.y * 256 + tid;

    const float4* kp = (const float4*)(Kp + base + (size_t)m * Dm);
    const float4* vp = (const float4*)(Vp + base + (size_t)m * Dm);
    float d0 = 0.f, d1 = 0.f, d2 = 0.f, d3 = 0.f;
    #pragma unroll
    for (int c = 0; c < 8; c += 4) {
        float4 k0 = kp[c+0], k1 = kp[c+1], k2 = kp[c+2], k3 = kp[c+3];
        d0 += q[c+0].x*k0.x + q[c+0].y*k0.y + q[c+0].z*k0.z + q[c+0].w*k0.w;
        d1 += q[c+1].x*k1.x + q[c+1].y*k1.y + q[c+1].z*k1.z + q[c+1].w*k1.w;
        d2 += q[c+2].x*k2.x + q[c+2].y*k2.y + q[c+2].z*k2.z + q[c+2].w*k2.w;
        d3 += q[c+3].x*k3.x + q[c+3].y*k3.y + q[c+3].z*k3.z + q[c+3].w*k3.w;
    }
    float dot = (d0 + d1) + (d2 + d3);
    float a = __builtin_amdgcn_rcpf(1.f + ex2(dot * NSC2));
    float4 acc[8];
    #pragma unroll
    for (int c = 0; c < 8; ++c) {
        float4 vv = vp[c];
        acc[c].x = a * vv.x; acc[c].y = a * vv.y; acc[c].z = a * vv.z; acc[c].w = a * vv.w;
    }
    #pragma unroll
    for (int off = 1; off < 64; off <<= 1) {
        #pragma unroll
        for (int c = 0; c < 8; ++c) {
            acc[c].x += __shfl_xor(acc[c].x, off);
            acc[c].y += __shfl_xor(acc[c].y, off);
            acc[c].z += __shfl_xor(acc[c].z, off);
            acc[c].w += __shfl_xor(acc[c].w, off);
        }
    }
    __shared__ float red[4][32];
    const int wave = tid >> 6, lane = tid & 63;
    if (lane == 0) {
        #pragma unroll
        for (int c = 0; c < 8; ++c) {
            red[wave][c*4+0] = acc[c].x; red[wave][c*4+1] = acc[c].y;
            red[wave][c*4+2] = acc[c].z; red[wave][c*4+3] = acc[c].w;
        }
    }
    __syncthreads();
    if (tid < 32) {
        float t = (red[0][tid] + red[1][tid]) + (red[2][tid] + red[3][tid]);
        if (blockIdx.y == 0) t += qs[tid];
        P0part[blockIdx.y * 512 + b * 128 + h * 32 + tid] = t;
    }
}

// ================= fused tail (UNCHANGED from R11, passing) =================
__global__ __launch_bounds__(256) void k_tail(const float* __restrict__ P0part,
                                              const float* __restrict__ W23, const float* __restrict__ b23,
                                              const float* __restrict__ pW, const float* __restrict__ pb,
                                              float* __restrict__ out) {
    const int b = blockIdx.x, tid = threadIdx.x;
    __shared__ float staged[128], pp[128];
    if (tid < 128) {
        float s = 0.f;
        #pragma unroll
        for (int ms = 0; ms < 8; ++ms) s += P0part[ms * 512 + b * 128 + tid];
        staged[tid] = s;
    }
    __syncthreads();
    if (tid < 128) {
        float acc = b23[tid];
        #pragma unroll 8
        for (int k = 0; k < 128; ++k)
            acc = fmaf(staged[k], W23[k * 128 + tid], acc);
        pp[tid] = fmaxf(acc, 0.f) + staged[tid];
    }
    __syncthreads();
    float a = pb[tid];
    #pragma unroll 8
    for (int k = 0; k < 128; ++k)
        a = fmaf(pp[k], pW[k * 256 + tid], a);
    out[b * 256 + tid] = a;
}

extern "C" void kernel_launch(void* const* d_in, const int* in_sizes, int n_in,
                              void* d_out, int out_size, void* d_ws, size_t ws_size,
                              hipStream_t stream) {
    const float* X = (const float*)d_in[0];
    auto W = [&](int i) { return (const float*)d_in[i]; };
    float* ws = (float*)d_ws;

    // f32 slots: s0: Qp0 -> K2   s1: Qp1 -> P0part   s2: Opart   s3: V2
    // bf16: Qb, Kh, Vt (SZ each), WtAll
    float* s0 = ws + 0 * SZ;
    float* s1 = ws + 1 * SZ;
    float* s2 = ws + 2 * SZ;
    float* s3 = ws + 3 * SZ;
    HB*    B4  = (HB*)(ws + 4 * SZ);
    HB*    Qb  = B4;
    HB*    Kbf = B4 + SZ;
    HB*    Vt  = B4 + 2 * SZ;
    HB*    WtAll = B4 + 3 * SZ;
    auto Wt = [&](int idx) { return (const HB*)(WtAll + (size_t)idx * 16384); };
    float* P0part = s1;

    const int GL = MN / 16;                  // 512 blocks
    const int attn_blocks = 512;
    dim3 wprep_grid(10, 4);
    dim3 pma_grid(Bn * Hh, 8);
    const float* nul = nullptr;
    HB* nulh = nullptr;

    k_wprep<<<wprep_grid, 256, 0, stream>>>(W(1), W(3), W(5), W(7), W(9), W(11), W(13), W(15),
                                            W(19), W(21), WtAll);

    // ---- SAB layer 0: QKV from X ----
    k_qkv<<<GL, 512, 0, stream>>>(X, Wt(0), W(2), Wt(1), W(4), Wt(2), W(6), s0, Qb, Kbf, Vt);
    k_attn4<<<attn_blocks, 512, 0, stream>>>(Qb, Kbf, Vt, s2);               // Opart0

    // ---- oproj0 (X1 in LDS) + QKV1 ----
    k_fused2<3,1><<<GL, 512, 0, stream>>>(s0, s2, Wt(3), W(8),
                                          Wt(4), W(10), Wt(5), W(12), Wt(6), W(14),
                                          s1, nullptr, Qb, Kbf, Vt);
    k_attn4<<<attn_blocks, 512, 0, stream>>>(Qb, Kbf, Vt, s2);               // Opart1

    // ---- oproj1 (X2 in LDS) + K2/V2 (f32) ----
    k_fused2<2,0><<<GL, 512, 0, stream>>>(s1, s2, Wt(7), W(16),
                                          Wt(8), W(20), Wt(9), W(22), nullptr, nul,
                                          s0, s3, nulh, nulh, nulh);

    // ---- PMA attention + tail ----
    k_pma2<<<pma_grid, 256, 0, stream>>>((const float*)d_in[25], W(17), W(18), s0, s3, P0part);
    k_tail<<<Bn, 256, 0, stream>>>(P0part, W(23), W(24), (const float*)d_in[26], (const float*)d_in[27],
                                   (float*)d_out);
}